// Round 6
// baseline (226.010 us; speedup 1.0000x reference)
//
#include <hip/hip_runtime.h>

#define EPS 1e-5f

typedef __attribute__((ext_vector_type(8))) short bf16x8;
typedef __attribute__((ext_vector_type(4))) float f32x4;

static __device__ __forceinline__ unsigned short f2bf(float f) {
  unsigned int u = __float_as_uint(f);
  u = u + 0x7FFFu + ((u >> 16) & 1u);   // round-nearest-even
  return (unsigned short)(u >> 16);
}
static __device__ __forceinline__ float bf2f(unsigned short h) {
  return __uint_as_float(((unsigned int)h) << 16);
}
static __device__ __forceinline__ unsigned int pk2(float lo, float hi) {
  return (unsigned int)f2bf(lo) | ((unsigned int)f2bf(hi) << 16);
}

// K1 (MFMA, swapped operands): D = Wfrag(A) * xfrag(B) so that D rows =
// output channels -> each lane holds 4 CONSECUTIVE channels of one point row
// => one 8B ushort4 store per tile (12 stores/thread vs 48 scalar 2B).
//   cols 0..63   -> Z bf16 (raw)
//   cols 64..191 -> Y bf16 (BN + ReLU fused)
// BM=64, BN=192, K=64 LDS-resident; swizzle byte ^= (row&7)<<4 both sides.
__global__ __launch_bounds__(256) void k1_mfma(
    const float* __restrict__ x, const float* __restrict__ W1,
    const float* __restrict__ Wl, const float* __restrict__ gl,
    const float* __restrict__ bl, const float* __restrict__ ml,
    const float* __restrict__ vl,
    unsigned short* __restrict__ Z, unsigned short* __restrict__ Y)
{
  __shared__ unsigned short As[64 * 64];    // [n][k]   8 KB
  __shared__ unsigned short Bs[192 * 64];   // [c][k]  24 KB
  char* Ab = reinterpret_cast<char*>(As);
  char* Bb = reinterpret_cast<char*>(Bs);

  const int t = threadIdx.x;
  const long row0 = (long)blockIdx.x * 64;

  // ---- stage B: W1 rows 3..66 -> Bs[c][k], c=0..63 ----
  {
    int k = t >> 2, c0 = (t & 3) * 16;
    const float4* w4 = reinterpret_cast<const float4*>(W1 + (size_t)(3 + k) * 64 + c0);
#pragma unroll
    for (int i = 0; i < 4; ++i) {
      float4 w = w4[i];
#pragma unroll
      for (int j = 0; j < 4; ++j) {
        int c = c0 + i * 4 + j;
        float v = (j == 0) ? w.x : (j == 1) ? w.y : (j == 2) ? w.z : w.w;
        int byte = c * 128 + ((2 * k) ^ ((c & 7) << 4));
        *reinterpret_cast<unsigned short*>(Bb + byte) = f2bf(v);
      }
    }
  }
  // ---- stage B: Wl[k][c] -> Bs[64+c][k], c=0..127 ----
  {
    int k = t >> 2, c0 = (t & 3) * 32;
    const float4* w4 = reinterpret_cast<const float4*>(Wl + (size_t)k * 128 + c0);
#pragma unroll
    for (int i = 0; i < 8; ++i) {
      float4 w = w4[i];
#pragma unroll
      for (int j = 0; j < 4; ++j) {
        int c = 64 + c0 + i * 4 + j;
        float v = (j == 0) ? w.x : (j == 1) ? w.y : (j == 2) ? w.z : w.w;
        int byte = c * 128 + ((2 * k) ^ ((c & 7) << 4));
        *reinterpret_cast<unsigned short*>(Bb + byte) = f2bf(v);
      }
    }
  }
  // ---- stage A: x rows row0..row0+63 (fp32 -> bf16) ----
  {
    const float4* xg = reinterpret_cast<const float4*>(x + row0 * 64);
#pragma unroll
    for (int i = 0; i < 4; ++i) {
      int idx = t + i * 256;            // float4 index in 64x64 tile
      float4 v = xg[idx];               // fully coalesced
      int r = idx >> 4;                 // 16 float4 per row
      int b0 = (idx & 15) * 8;
      int byte = r * 128 + (b0 ^ ((r & 7) << 4));
      uint2 pkv = make_uint2(pk2(v.x, v.y), pk2(v.z, v.w));
      *reinterpret_cast<uint2*>(Ab + byte) = pkv;
    }
  }
  __syncthreads();

  const int wid = t >> 6, lane = t & 63;
  const int roff = (wid & 1) * 32, coff = (wid >> 1) * 96;
  const int lr = lane & 15, lk = lane >> 4;

  // x fragments (B operand): n = roff + rt*16 + lr, k = ks*32 + lk*8 + i
  bf16x8 af[2][2];
#pragma unroll
  for (int rt = 0; rt < 2; ++rt) {
    int r = roff + rt * 16 + lr;
#pragma unroll
    for (int ks = 0; ks < 2; ++ks) {
      int byte = r * 128 + ((ks * 64 + lk * 16) ^ ((r & 7) << 4));
      af[rt][ks] = *reinterpret_cast<const bf16x8*>(Ab + byte);
    }
  }

#pragma unroll
  for (int ct = 0; ct < 6; ++ct) {
    int c0t = coff + ct * 16;           // tile col base (wave-uniform)
    int cread = c0t + lr;               // W frag (A operand): row = channel
    int byte0 = cread * 128 + ((lk * 16) ^ ((cread & 7) << 4));
    int byte1 = cread * 128 + ((64 + lk * 16) ^ ((cread & 7) << 4));
    bf16x8 bf0 = *reinterpret_cast<const bf16x8*>(Bb + byte0);
    bf16x8 bf1 = *reinterpret_cast<const bf16x8*>(Bb + byte1);

    // BN constants for this lane's 4 output channels (Y region only)
    float sc0 = 1.f, sc1 = 1.f, sc2 = 1.f, sc3 = 1.f;
    float sh0 = 0.f, sh1 = 0.f, sh2 = 0.f, sh3 = 0.f;
    if (c0t >= 64) {
      int oc = c0t - 64 + lk * 4;
      float4 g4 = *reinterpret_cast<const float4*>(gl + oc);
      float4 v4 = *reinterpret_cast<const float4*>(vl + oc);
      float4 b4 = *reinterpret_cast<const float4*>(bl + oc);
      float4 m4 = *reinterpret_cast<const float4*>(ml + oc);
      sc0 = g4.x * rsqrtf(v4.x + EPS); sh0 = b4.x - m4.x * sc0;
      sc1 = g4.y * rsqrtf(v4.y + EPS); sh1 = b4.y - m4.y * sc1;
      sc2 = g4.z * rsqrtf(v4.z + EPS); sh2 = b4.z - m4.z * sc2;
      sc3 = g4.w * rsqrtf(v4.w + EPS); sh3 = b4.w - m4.w * sc3;
    }
#pragma unroll
    for (int rt = 0; rt < 2; ++rt) {
      f32x4 acc = {0.f, 0.f, 0.f, 0.f};
      acc = __builtin_amdgcn_mfma_f32_16x16x32_bf16(bf0, af[rt][0], acc, 0, 0, 0);
      acc = __builtin_amdgcn_mfma_f32_16x16x32_bf16(bf1, af[rt][1], acc, 0, 0, 0);
      // D: col(lane&15)=point row, row(lk*4+q)=channel -> 4 consecutive ch
      long n = row0 + roff + rt * 16 + lr;
      if (c0t < 64) {
        int cb = c0t + lk * 4;
        *reinterpret_cast<ushort4*>(Z + n * 64 + cb) =
            make_ushort4(f2bf(acc[0]), f2bf(acc[1]), f2bf(acc[2]), f2bf(acc[3]));
      } else {
        int cb = c0t - 64 + lk * 4;
        float y0 = fmaxf(fmaf(acc[0], sc0, sh0), 0.f);
        float y1 = fmaxf(fmaf(acc[1], sc1, sh1), 0.f);
        float y2 = fmaxf(fmaf(acc[2], sc2, sh2), 0.f);
        float y3 = fmaxf(fmaf(acc[3], sc3, sh3), 0.f);
        *reinterpret_cast<ushort4*>(Y + n * 128 + cb) =
            make_ushort4(f2bf(y0), f2bf(y1), f2bf(y2), f2bf(y3));
      }
    }
  }
}

// packed combine: merge two 64-lane partial sums, halving lanes per value.
// result: lanes with (lane&off)==0 hold a reduced over bit, others hold b.
static __device__ __forceinline__ float comb(float a, float b, int off, int lane) {
  bool hi = (lane & off) != 0;
  float send = hi ? a : b;
  float t = __shfl_xor(send, off, 64);
  return (hi ? b : a) + t;
}

// K2: one wave per center m. Packed reduction tree: 16 k-sums in 17 shuffles
// (vs 96), softmax weights broadcast via constant-lane shfl.
__global__ __launch_bounds__(256) void k2_gather(
    const float* __restrict__ p, const unsigned short* __restrict__ Z,
    const unsigned short* __restrict__ Y, const float* __restrict__ W1,
    const float* __restrict__ g1, const float* __restrict__ b1,
    const float* __restrict__ m1, const float* __restrict__ v1,
    const float* __restrict__ W2, const int* __restrict__ idx,
    const int* __restrict__ knn, float* __restrict__ out_np,
    float* __restrict__ out_feat, int M)
{
  int gtid = blockIdx.x * 256 + threadIdx.x;
  int wid = gtid >> 6;
  int lane = threadIdx.x & 63;
  if (wid >= M) return;
  int m = __builtin_amdgcn_readfirstlane(wid);

  float a1 = g1[lane] * rsqrtf(v1[lane] + EPS);
  float c1 = b1[lane] - m1[lane] * a1;
  float w2 = W2[lane];
  float w10 = W1[lane];
  float w11 = W1[64 + lane];
  float w12 = W1[128 + lane];

  int ic = idx[m];
  float cx = p[ic * 3 + 0];
  float cy = p[ic * 3 + 1];
  float cz = p[ic * 3 + 2];
  if (lane < 3) {
    float v = (lane == 0) ? cx : ((lane == 1) ? cy : cz);
    out_np[(size_t)m * 3 + lane] = v;
  }

  float part[16];
  int jj[16];
#pragma unroll
  for (int k = 0; k < 16; ++k) {
    int j = knn[m * 16 + k];     // uniform -> scalar load
    jj[k] = j;
    float rx = p[j * 3 + 0] - cx;
    float ry = p[j * 3 + 1] - cy;
    float rz = p[j * 3 + 2] - cz;
    float tv = bf2f(Z[(size_t)j * 64 + lane]);   // coalesced 128B row
    tv = fmaf(rx, w10, tv);
    tv = fmaf(ry, w11, tv);
    tv = fmaf(rz, w12, tv);
    float h = fmaxf(fmaf(tv, a1, c1), 0.f);
    part[k] = h * w2;
  }

  // reduction tree: k bit0->lane bit5, bit1->bit4, bit2->bit3, bit3->bit2
  float u[8];
#pragma unroll
  for (int i = 0; i < 8; ++i) u[i] = comb(part[2 * i], part[2 * i + 1], 32, lane);
  float v4[4];
#pragma unroll
  for (int i = 0; i < 4; ++i) v4[i] = comb(u[2 * i], u[2 * i + 1], 16, lane);
  float w4[2];
#pragma unroll
  for (int i = 0; i < 2; ++i) w4[i] = comb(v4[2 * i], v4[2 * i + 1], 8, lane);
  float s1 = comb(w4[0], w4[1], 4, lane);
  s1 += __shfl_xor(s1, 1, 64);
  s1 += __shfl_xor(s1, 2, 64);
  // now 4-lane group g = lane>>2 holds s[k] with k = bitrev4(g)

  // max over the 16 values (butterfly on the packed register)
  float mx = s1;
  mx = fmaxf(mx, __shfl_xor(mx, 4, 64));
  mx = fmaxf(mx, __shfl_xor(mx, 8, 64));
  mx = fmaxf(mx, __shfl_xor(mx, 16, 64));
  mx = fmaxf(mx, __shfl_xor(mx, 32, 64));
  float e = __expf(s1 - mx);

  // broadcast the 16 exp-weights (constant source lanes) + denominator
  float pk[16];
  float S = 0.f;
#pragma unroll
  for (int k = 0; k < 16; ++k) {
    int g = ((k & 1) << 3) | ((k & 2) << 1) | ((k & 4) >> 1) | ((k & 8) >> 3);
    pk[k] = __shfl(e, g * 4, 64);
    S += pk[k];
  }
  float inv = 1.f / S;

  // weighted sum of Y rows; lane owns channels 2*lane, 2*lane+1
  float acc0 = 0.f, acc1 = 0.f;
#pragma unroll
  for (int k = 0; k < 16; ++k) {
    const unsigned short* yr = Y + (size_t)jj[k] * 128;
    unsigned int uu = *reinterpret_cast<const unsigned int*>(yr + 2 * lane);
    acc0 = fmaf(pk[k], bf2f((unsigned short)(uu & 0xFFFFu)), acc0);
    acc1 = fmaf(pk[k], bf2f((unsigned short)(uu >> 16)), acc1);
  }
  float* orow = out_feat + (size_t)m * 128;
  *reinterpret_cast<float2*>(orow + 2 * lane) =
      make_float2(acc0 * inv, acc1 * inv);
}

extern "C" void kernel_launch(void* const* d_in, const int* in_sizes, int n_in,
                              void* d_out, int out_size, void* d_ws, size_t ws_size,
                              hipStream_t stream) {
  const float* p  = (const float*)d_in[0];
  const float* x  = (const float*)d_in[1];
  const float* W1 = (const float*)d_in[2];
  const float* g1 = (const float*)d_in[3];
  const float* b1 = (const float*)d_in[4];
  const float* m1 = (const float*)d_in[5];
  const float* v1 = (const float*)d_in[6];
  const float* W2 = (const float*)d_in[7];
  // d_in[8] = b2: softmax shift-invariant -> unused
  const float* Wl = (const float*)d_in[9];
  const float* gl = (const float*)d_in[10];
  const float* bl = (const float*)d_in[11];
  const float* ml = (const float*)d_in[12];
  const float* vl = (const float*)d_in[13];
  const int* idx  = (const int*)d_in[14];
  const int* knn  = (const int*)d_in[15];

  const int N = in_sizes[1] / 64;    // 200000 (divisible by 64)
  const int M = in_sizes[14];        // 50000

  unsigned short* Z = (unsigned short*)d_ws;                  // [N,64]  bf16
  unsigned short* Y = Z + (size_t)N * 64;                     // [N,128] bf16
  float* out_np   = (float*)d_out;                            // [M,3]
  float* out_feat = out_np + (size_t)M * 3;                   // [M,128]

  k1_mfma<<<dim3(N / 64), dim3(256), 0, stream>>>(
      x, W1, Wl, gl, bl, ml, vl, Z, Y);
  k2_gather<<<dim3(((size_t)M * 64 + 255) / 256), dim3(256), 0, stream>>>(
      p, Z, Y, W1, g1, b1, m1, v1, W2, idx, knn, out_np, out_feat, M);
}

// Round 7
// 205.279 us; speedup vs baseline: 1.1010x; 1.1010x over previous
//
#include <hip/hip_runtime.h>

#define EPS 1e-5f

typedef __attribute__((ext_vector_type(8))) short bf16x8;
typedef __attribute__((ext_vector_type(4))) float f32x4;

static __device__ __forceinline__ unsigned short f2bf(float f) {
  unsigned int u = __float_as_uint(f);
  u = u + 0x7FFFu + ((u >> 16) & 1u);   // round-nearest-even
  return (unsigned short)(u >> 16);
}
static __device__ __forceinline__ float bf2f(unsigned short h) {
  return __uint_as_float(((unsigned int)h) << 16);
}
static __device__ __forceinline__ unsigned int pk2(float lo, float hi) {
  return (unsigned int)f2bf(lo) | ((unsigned int)f2bf(hi) << 16);
}

// K1 (MFMA, swapped operands): D = Wfrag(A) * xfrag(B); lane holds 4
// consecutive output channels of one point row => 8B ushort4 stores.
//   cols 0..63   -> Z bf16 (raw),  cols 64..191 -> Y bf16 (BN+ReLU)
// Staging rewritten to packed ds_write_b128 (8 DS ops/thread vs 52).
__global__ __launch_bounds__(256) void k1_mfma(
    const float* __restrict__ x, const float* __restrict__ W1,
    const float* __restrict__ Wl, const float* __restrict__ gl,
    const float* __restrict__ bl, const float* __restrict__ ml,
    const float* __restrict__ vl,
    unsigned short* __restrict__ Z, unsigned short* __restrict__ Y)
{
  __shared__ unsigned short As[64 * 64];    // [n][k]   8 KB
  __shared__ unsigned short Bs[192 * 64];   // [c][k]  24 KB
  char* Ab = reinterpret_cast<char*>(As);
  char* Bb = reinterpret_cast<char*>(Bs);

  const int t = threadIdx.x;
  const long row0 = (long)blockIdx.x * 64;

  // ---- stage B: W1 rows 3..66 -> Bs[c][k] (c=0..63), column reads ----
  {
    int c = t & 63, k0 = (t >> 6) * 16;   // wave-uniform k0, lane=c: coalesced
    unsigned int w[8];
#pragma unroll
    for (int i = 0; i < 8; ++i) {
      float lo = W1[(size_t)(3 + k0 + 2 * i) * 64 + c];
      float hi = W1[(size_t)(3 + k0 + 2 * i + 1) * 64 + c];
      w[i] = pk2(lo, hi);
    }
    int byte0 = c * 128 + ((2 * k0) ^ ((c & 7) << 4));
    int byte1 = c * 128 + ((2 * (k0 + 8)) ^ ((c & 7) << 4));
    *reinterpret_cast<uint4*>(Bb + byte0) = make_uint4(w[0], w[1], w[2], w[3]);
    *reinterpret_cast<uint4*>(Bb + byte1) = make_uint4(w[4], w[5], w[6], w[7]);
  }
  // ---- stage B: Wl -> Bs[64+c][k] (c=0..127), column reads ----
  {
    int c = t & 127, kh = t >> 7;         // kh in {0,1}; lanes -> consecutive c
    int cc = 64 + c;
#pragma unroll
    for (int g = 0; g < 4; ++g) {
      unsigned int w[4];
#pragma unroll
      for (int i = 0; i < 4; ++i) {
        int k = kh * 32 + g * 8 + 2 * i;
        float lo = Wl[(size_t)k * 128 + c];
        float hi = Wl[(size_t)(k + 1) * 128 + c];
        w[i] = pk2(lo, hi);
      }
      int byte = cc * 128 + ((2 * (kh * 32 + g * 8)) ^ ((cc & 7) << 4));
      *reinterpret_cast<uint4*>(Bb + byte) = make_uint4(w[0], w[1], w[2], w[3]);
    }
  }
  // ---- stage A: x rows row0..row0+63 (fp32 -> bf16), 16B writes ----
  {
    const float4* xg = reinterpret_cast<const float4*>(x + row0 * 64);
#pragma unroll
    for (int i = 0; i < 2; ++i) {
      int pi = t + i * 256;               // 16B-chunk index (512 total)
      int r = pi >> 3, q = pi & 7;
      float4 v0 = xg[pi * 2];
      float4 v1 = xg[pi * 2 + 1];
      int byte = r * 128 + ((q * 16) ^ ((r & 7) << 4));
      *reinterpret_cast<uint4*>(Ab + byte) =
          make_uint4(pk2(v0.x, v0.y), pk2(v0.z, v0.w),
                     pk2(v1.x, v1.y), pk2(v1.z, v1.w));
    }
  }
  __syncthreads();

  const int wid = t >> 6, lane = t & 63;
  const int roff = (wid & 1) * 32, coff = (wid >> 1) * 96;
  const int lr = lane & 15, lk = lane >> 4;

  // x fragments (B operand): n = roff + rt*16 + lr, k = ks*32 + lk*8 + i
  bf16x8 af[2][2];
#pragma unroll
  for (int rt = 0; rt < 2; ++rt) {
    int r = roff + rt * 16 + lr;
#pragma unroll
    for (int ks = 0; ks < 2; ++ks) {
      int byte = r * 128 + ((ks * 64 + lk * 16) ^ ((r & 7) << 4));
      af[rt][ks] = *reinterpret_cast<const bf16x8*>(Ab + byte);
    }
  }

#pragma unroll
  for (int ct = 0; ct < 6; ++ct) {
    int c0t = coff + ct * 16;             // tile col base (wave-uniform)
    int cread = c0t + lr;                 // W frag (A operand): row = channel
    int byte0 = cread * 128 + ((lk * 16) ^ ((cread & 7) << 4));
    int byte1 = cread * 128 + ((64 + lk * 16) ^ ((cread & 7) << 4));
    bf16x8 bf0 = *reinterpret_cast<const bf16x8*>(Bb + byte0);
    bf16x8 bf1 = *reinterpret_cast<const bf16x8*>(Bb + byte1);

    float sc0 = 1.f, sc1 = 1.f, sc2 = 1.f, sc3 = 1.f;
    float sh0 = 0.f, sh1 = 0.f, sh2 = 0.f, sh3 = 0.f;
    if (c0t >= 64) {
      int oc = c0t - 64 + lk * 4;
      float4 g4 = *reinterpret_cast<const float4*>(gl + oc);
      float4 v4 = *reinterpret_cast<const float4*>(vl + oc);
      float4 b4 = *reinterpret_cast<const float4*>(bl + oc);
      float4 m4 = *reinterpret_cast<const float4*>(ml + oc);
      sc0 = g4.x * rsqrtf(v4.x + EPS); sh0 = b4.x - m4.x * sc0;
      sc1 = g4.y * rsqrtf(v4.y + EPS); sh1 = b4.y - m4.y * sc1;
      sc2 = g4.z * rsqrtf(v4.z + EPS); sh2 = b4.z - m4.z * sc2;
      sc3 = g4.w * rsqrtf(v4.w + EPS); sh3 = b4.w - m4.w * sc3;
    }
#pragma unroll
    for (int rt = 0; rt < 2; ++rt) {
      f32x4 acc = {0.f, 0.f, 0.f, 0.f};
      acc = __builtin_amdgcn_mfma_f32_16x16x32_bf16(bf0, af[rt][0], acc, 0, 0, 0);
      acc = __builtin_amdgcn_mfma_f32_16x16x32_bf16(bf1, af[rt][1], acc, 0, 0, 0);
      long n = row0 + roff + rt * 16 + lr;
      if (c0t < 64) {
        int cb = c0t + lk * 4;
        *reinterpret_cast<ushort4*>(Z + n * 64 + cb) =
            make_ushort4(f2bf(acc[0]), f2bf(acc[1]), f2bf(acc[2]), f2bf(acc[3]));
      } else {
        int cb = c0t - 64 + lk * 4;
        float y0 = fmaxf(fmaf(acc[0], sc0, sh0), 0.f);
        float y1 = fmaxf(fmaf(acc[1], sc1, sh1), 0.f);
        float y2 = fmaxf(fmaf(acc[2], sc2, sh2), 0.f);
        float y3 = fmaxf(fmaf(acc[3], sc3, sh3), 0.f);
        *reinterpret_cast<ushort4*>(Y + n * 128 + cb) =
            make_ushort4(f2bf(y0), f2bf(y1), f2bf(y2), f2bf(y3));
      }
    }
  }
}

// packed combine: merge two 64-lane partial sums, halving lanes per value.
static __device__ __forceinline__ float comb(float a, float b, int off, int lane) {
  bool hi = (lane & off) != 0;
  float send = hi ? a : b;
  float t = __shfl_xor(send, off, 64);
  return (hi ? b : a) + t;
}

// K2: one wave per center m. Load-batched: all 16 Z + all 16 Y gathers are
// issued into registers up front (32 VMEM in flight); softmax tree runs
// while Y loads land.
__global__ __launch_bounds__(256) void k2_gather(
    const float* __restrict__ p, const unsigned short* __restrict__ Z,
    const unsigned short* __restrict__ Y, const float* __restrict__ W1,
    const float* __restrict__ g1, const float* __restrict__ b1,
    const float* __restrict__ m1, const float* __restrict__ v1,
    const float* __restrict__ W2, const int* __restrict__ idx,
    const int* __restrict__ knn, float* __restrict__ out_np,
    float* __restrict__ out_feat, int M)
{
  int gtid = blockIdx.x * 256 + threadIdx.x;
  int wid = gtid >> 6;
  int lane = threadIdx.x & 63;
  if (wid >= M) return;
  int m = __builtin_amdgcn_readfirstlane(wid);

  // uniform scalar context: center + 16 neighbor indices + their xyz
  int ic = idx[m];
  float cx = p[ic * 3 + 0];
  float cy = p[ic * 3 + 1];
  float cz = p[ic * 3 + 2];

  int jj[16];
#pragma unroll
  for (int k = 0; k < 16; ++k) jj[k] = knn[m * 16 + k];   // uniform s_loads

  float px[16], py[16], pz[16];
#pragma unroll
  for (int k = 0; k < 16; ++k) {
    px[k] = p[jj[k] * 3 + 0];
    py[k] = p[jj[k] * 3 + 1];
    pz[k] = p[jj[k] * 3 + 2];
  }

  // issue ALL Z gathers (coalesced 128B rows)
  unsigned short zv[16];
#pragma unroll
  for (int k = 0; k < 16; ++k) zv[k] = Z[(size_t)jj[k] * 64 + lane];

  // issue ALL Y gathers (coalesced 256B rows); consumed only after softmax
  unsigned int yv[16];
#pragma unroll
  for (int k = 0; k < 16; ++k)
    yv[k] = *reinterpret_cast<const unsigned int*>(Y + (size_t)jj[k] * 128 + 2 * lane);

  // per-lane (channel) constants
  float a1 = g1[lane] * rsqrtf(v1[lane] + EPS);
  float c1 = b1[lane] - m1[lane] * a1;
  float w2 = W2[lane];
  float w10 = W1[lane];
  float w11 = W1[64 + lane];
  float w12 = W1[128 + lane];

  if (lane < 3) {
    float v = (lane == 0) ? cx : ((lane == 1) ? cy : cz);
    out_np[(size_t)m * 3 + lane] = v;
  }

  // shrinker MLP partials (VALU only; zv already landing)
  float part[16];
#pragma unroll
  for (int k = 0; k < 16; ++k) {
    float tv = bf2f(zv[k]);
    tv = fmaf(px[k] - cx, w10, tv);
    tv = fmaf(py[k] - cy, w11, tv);
    tv = fmaf(pz[k] - cz, w12, tv);
    float h = fmaxf(fmaf(tv, a1, c1), 0.f);
    part[k] = h * w2;
  }

  // reduction tree: k bit0->lane bit5, bit1->bit4, bit2->bit3, bit3->bit2
  float u[8];
#pragma unroll
  for (int i = 0; i < 8; ++i) u[i] = comb(part[2 * i], part[2 * i + 1], 32, lane);
  float v4[4];
#pragma unroll
  for (int i = 0; i < 4; ++i) v4[i] = comb(u[2 * i], u[2 * i + 1], 16, lane);
  float w4[2];
#pragma unroll
  for (int i = 0; i < 2; ++i) w4[i] = comb(v4[2 * i], v4[2 * i + 1], 8, lane);
  float s1 = comb(w4[0], w4[1], 4, lane);
  s1 += __shfl_xor(s1, 1, 64);
  s1 += __shfl_xor(s1, 2, 64);
  // 4-lane group g = lane>>2 holds s[k], k = bitrev4(g)

  float mx = s1;
  mx = fmaxf(mx, __shfl_xor(mx, 4, 64));
  mx = fmaxf(mx, __shfl_xor(mx, 8, 64));
  mx = fmaxf(mx, __shfl_xor(mx, 16, 64));
  mx = fmaxf(mx, __shfl_xor(mx, 32, 64));
  float e = __expf(s1 - mx);

  float pw[16];
  float S = 0.f;
#pragma unroll
  for (int k = 0; k < 16; ++k) {
    int g = ((k & 1) << 3) | ((k & 2) << 1) | ((k & 4) >> 1) | ((k & 8) >> 3);
    pw[k] = __shfl(e, g * 4, 64);
    S += pw[k];
  }
  float inv = 1.f / S;

  // weighted sum of (already-loaded) Y rows; lane owns ch 2*lane, 2*lane+1
  float acc0 = 0.f, acc1 = 0.f;
#pragma unroll
  for (int k = 0; k < 16; ++k) {
    acc0 = fmaf(pw[k], bf2f((unsigned short)(yv[k] & 0xFFFFu)), acc0);
    acc1 = fmaf(pw[k], bf2f((unsigned short)(yv[k] >> 16)), acc1);
  }
  float* orow = out_feat + (size_t)m * 128;
  *reinterpret_cast<float2*>(orow + 2 * lane) =
      make_float2(acc0 * inv, acc1 * inv);
}

extern "C" void kernel_launch(void* const* d_in, const int* in_sizes, int n_in,
                              void* d_out, int out_size, void* d_ws, size_t ws_size,
                              hipStream_t stream) {
  const float* p  = (const float*)d_in[0];
  const float* x  = (const float*)d_in[1];
  const float* W1 = (const float*)d_in[2];
  const float* g1 = (const float*)d_in[3];
  const float* b1 = (const float*)d_in[4];
  const float* m1 = (const float*)d_in[5];
  const float* v1 = (const float*)d_in[6];
  const float* W2 = (const float*)d_in[7];
  // d_in[8] = b2: softmax shift-invariant -> unused
  const float* Wl = (const float*)d_in[9];
  const float* gl = (const float*)d_in[10];
  const float* bl = (const float*)d_in[11];
  const float* ml = (const float*)d_in[12];
  const float* vl = (const float*)d_in[13];
  const int* idx  = (const int*)d_in[14];
  const int* knn  = (const int*)d_in[15];

  const int N = in_sizes[1] / 64;    // 200000 (divisible by 64)
  const int M = in_sizes[14];        // 50000

  unsigned short* Z = (unsigned short*)d_ws;                  // [N,64]  bf16
  unsigned short* Y = Z + (size_t)N * 64;                     // [N,128] bf16
  float* out_np   = (float*)d_out;                            // [M,3]
  float* out_feat = out_np + (size_t)M * 3;                   // [M,128]

  k1_mfma<<<dim3(N / 64), dim3(256), 0, stream>>>(
      x, W1, Wl, gl, bl, ml, vl, Z, Y);
  k2_gather<<<dim3(((size_t)M * 64 + 255) / 256), dim3(256), 0, stream>>>(
      p, Z, Y, W1, g1, b1, m1, v1, W2, idx, knn, out_np, out_feat, M);
}